// Round 10
// baseline (521.332 us; speedup 1.0000x reference)
//
#include <hip/hip_runtime.h>

#define NN 100000
#define NE 1600000
#define DD 128
#define BN_EPS 1e-5f
#define NB 391       // scan blocks: 391*256 = 100096 >= NN
#define MB 1563      // gemm blocks: 1563*64 >= NN
#define DRANGE (NN / 8)   // 12500 dst nodes per XCD group

typedef __attribute__((ext_vector_type(8))) short short8v;
typedef __attribute__((ext_vector_type(4))) float float4v;

__device__ inline unsigned short f2bf(float f) {
  unsigned u = __float_as_uint(f);
  return (unsigned short)((u + 0x7FFF + ((u >> 16) & 1)) >> 16);  // RNE
}
__device__ inline short8v pack8(float4 a, float4 b) {
  short8v o;
  o[0] = (short)f2bf(a.x); o[1] = (short)f2bf(a.y);
  o[2] = (short)f2bf(a.z); o[3] = (short)f2bf(a.w);
  o[4] = (short)f2bf(b.x); o[5] = (short)f2bf(b.y);
  o[6] = (short)f2bf(b.z); o[7] = (short)f2bf(b.w);
  return o;
}

// ---------------------------------------------------------------------------
// Phase 0: x (fp32) -> x16 (bf16), one pass.
// ---------------------------------------------------------------------------
__global__ __launch_bounds__(256) void x2bf_kernel(
    const float* __restrict__ x, unsigned short* __restrict__ x16) {
  int i = blockIdx.x * 256 + threadIdx.x;       // one short8 per thread
  if (i >= NN * DD / 8) return;
  float4 f0 = reinterpret_cast<const float4*>(x)[(size_t)i * 2];
  float4 f1 = reinterpret_cast<const float4*>(x)[(size_t)i * 2 + 1];
  reinterpret_cast<short8v*>(x16)[i] = pack8(f0, f1);
}

// ---------------------------------------------------------------------------
// Phase 1a: histogram of dst degrees
// ---------------------------------------------------------------------------
__global__ __launch_bounds__(256) void hist_kernel(
    const int* __restrict__ ei, int* __restrict__ deg) {
  int e = blockIdx.x * 256 + threadIdx.x;
  if (e >= NE) return;
  atomicAdd(&deg[ei[NE + e]], 1);
}

// ---------------------------------------------------------------------------
// Phase 1b: device-wide exclusive scan of deg, 3 tiny kernels.
// ---------------------------------------------------------------------------
__global__ __launch_bounds__(256) void scan_part_kernel(
    const int* __restrict__ deg, int* __restrict__ bsum) {
  __shared__ int sc[256];
  int t = threadIdx.x;
  int i = blockIdx.x * 256 + t;
  int v = (i < NN) ? deg[i] : 0;
  sc[t] = v;
  __syncthreads();
  #pragma unroll
  for (int d = 1; d < 256; d <<= 1) {
    int u = (t >= d) ? sc[t - d] : 0;
    __syncthreads();
    sc[t] += u;
    __syncthreads();
  }
  if (t == 255) bsum[blockIdx.x] = sc[255];
}

__global__ __launch_bounds__(512) void scan_block_kernel(
    int* __restrict__ bsum, int* __restrict__ bofs) {
  __shared__ int sc[512];
  int t = threadIdx.x;
  int v = (t < NB) ? bsum[t] : 0;
  sc[t] = v;
  __syncthreads();
  #pragma unroll
  for (int d = 1; d < 512; d <<= 1) {
    int u = (t >= d) ? sc[t - d] : 0;
    __syncthreads();
    sc[t] += u;
    __syncthreads();
  }
  if (t < NB) bofs[t] = sc[t] - v;   // exclusive
}

__global__ __launch_bounds__(256) void scan_write_kernel(
    const int* __restrict__ deg, const int* __restrict__ bofs,
    int* __restrict__ offs, int* __restrict__ cursor) {
  __shared__ int sc[256];
  int t = threadIdx.x;
  int i = blockIdx.x * 256 + t;
  int v = (i < NN) ? deg[i] : 0;
  sc[t] = v;
  __syncthreads();
  #pragma unroll
  for (int d = 1; d < 256; d <<= 1) {
    int u = (t >= d) ? sc[t - d] : 0;
    __syncthreads();
    sc[t] += u;
    __syncthreads();
  }
  if (i < NN) {
    int excl = sc[t] - v + bofs[blockIdx.x];
    offs[i] = excl;
    cursor[i] = excl;
  }
}

// ---------------------------------------------------------------------------
// Phase 1c: bucket edges by dst, XCD-partitioned. Block group s = blockIdx&7
// handles only dst in [s*12500, (s+1)*12500): all stores to that contiguous
// sorted[] sub-region come from one XCD (blockIdx%8 -> XCD round-robin), so
// its L2 merges the 64B lines and writes each back once. Each group scans the
// full edge list (ei/ew are L3-resident; HBM fetches them once).
// Payload: (src:17b << 15) | bf16(w):15b  (w >= 0, sign bit free).
// ---------------------------------------------------------------------------
__global__ __launch_bounds__(256) void bucket_kernel(
    const int* __restrict__ ei, const float* __restrict__ ew,
    int* __restrict__ cursor, unsigned* __restrict__ sorted) {
  const int grp = blockIdx.x & 7;
  const int gth = (blockIdx.x >> 3) * 256 + threadIdx.x;   // 0..65535
  const int dlo = grp * DRANGE;
  const int dhi = dlo + DRANGE;
  for (int e = gth; e < NE; e += 65536) {
    int dst = ei[NE + e];
    if (dst < dlo || dst >= dhi) continue;
    int src = ei[e];
    unsigned w15 = f2bf(ew[e]);
    int pos = atomicAdd(&cursor[dst], 1);
    sorted[pos] = ((unsigned)src << 15) | w15;
  }
}

// ---------------------------------------------------------------------------
// Pack [Wrel; Wroot] (256x128 fp32) into MFMA-B fragment order, bf16.
// Frag (n, ks): lane l, j=0..7 -> B[ks*32 + (l>>4)*8 + j][n*16 + (l&15)].
// ---------------------------------------------------------------------------
__global__ __launch_bounds__(256) void pack_w_kernel(
    const float* __restrict__ Wrel, const float* __restrict__ Wroot,
    unsigned short* __restrict__ wpack) {
  int n = blockIdx.x;                 // 0..7
  for (int idx = threadIdx.x; idx < 8 * 64; idx += 256) {
    int ks = idx >> 6;
    int l = idx & 63;
    int srcN = n * 16 + (l & 15);
    short8v o;
    #pragma unroll
    for (int j = 0; j < 8; ++j) {
      int srcK = ks * 32 + ((l >> 4) << 3) + j;
      float v = (srcK < DD) ? Wrel[srcK * DD + srcN]
                            : Wroot[(srcK - DD) * DD + srcN];
      o[j] = (short)f2bf(v);
    }
    *reinterpret_cast<short8v*>(&wpack[(((size_t)(n * 8 + ks)) * 64 + l) * 8]) = o;
  }
}

// ---------------------------------------------------------------------------
// Phase 2 (fused): gather-aggregate + MFMA GEMM + BN stats.
// Block = 4 waves x 16 rows = 64 nodes. Per wave: 16 nodes sequentially;
// lanes 0-31 even edges / 32-63 odd edges, 8 B/lane (4 bf16 cols) from x16;
// fp32 accumulate; halves combined via __shfl_xor; result written bf16 into
// the LDS A-tile cols 0..127. Own features x16 -> cols 128..255. Then
// h = A @ wpack + b_rel via mfma_f32_16x16x32_bf16 (K=256, 8 k-steps),
// fused BN statistics, h written fp32 to d_out.
// ---------------------------------------------------------------------------
__global__ __launch_bounds__(256) void fused_aggr_gemm_bn_kernel(
    const unsigned short* __restrict__ x16, const unsigned* __restrict__ sorted,
    const int* __restrict__ offs, const int* __restrict__ cursor,
    const unsigned short* __restrict__ wpack, const float* __restrict__ brel,
    float* __restrict__ h, float* __restrict__ gsum, float* __restrict__ gsq) {
  __shared__ short Als[64 * 264];   // 33792 B (256 cols + 8 pad per row)
  __shared__ float s_sum[DD];
  __shared__ float s_sq[DD];

  const int t = threadIdx.x;
  const int row0 = blockIdx.x * 64;
  if (t < DD) { s_sum[t] = 0.f; s_sq[t] = 0.f; }

  const int w = t >> 6;       // wave 0..3
  const int l = t & 63;
  const int half = l >> 5;    // 0: even edges, 1: odd edges
  const int l32 = l & 31;     // col group: cols l32*4 .. l32*4+3
  const uint2* xp = reinterpret_cast<const uint2*>(x16);

  // Phase A: gather-aggregate, 16 nodes per wave -> A-tile cols 0..127
  for (int j = 0; j < 16; ++j) {
    int node = row0 + w * 16 + j;
    float a0 = 0.f, a1 = 0.f, a2 = 0.f, a3 = 0.f;
    if (node < NN) {
      int s = offs[node];
      int e = cursor[node];
      for (int i = s + half; i < e; i += 2) {
        unsigned p = sorted[i];
        float wt = __uint_as_float((p & 0x7FFFu) << 16);
        unsigned src = p >> 15;
        uint2 v = xp[(size_t)src * 32 + l32];
        a0 += wt * __uint_as_float(v.x << 16);
        a1 += wt * __uint_as_float(v.x & 0xFFFF0000u);
        a2 += wt * __uint_as_float(v.y << 16);
        a3 += wt * __uint_as_float(v.y & 0xFFFF0000u);
      }
    }
    a0 += __shfl_xor(a0, 32, 64);
    a1 += __shfl_xor(a1, 32, 64);
    a2 += __shfl_xor(a2, 32, 64);
    a3 += __shfl_xor(a3, 32, 64);
    if (half == 0) {
      ushort4 o;
      o.x = f2bf(a0); o.y = f2bf(a1); o.z = f2bf(a2); o.w = f2bf(a3);
      *reinterpret_cast<ushort4*>(&Als[(w * 16 + j) * 264 + l32 * 4]) = o;
    }
  }

  // Phase A2: own features (bf16) -> A-tile cols 128..255
  for (int i = t; i < 64 * 16; i += 256) {
    int r = i >> 4;
    int g = i & 15;
    int grow = row0 + r;
    short8v val = (short8v)0;
    if (grow < NN)
      val = *reinterpret_cast<const short8v*>(&x16[(size_t)grow * DD + g * 8]);
    *reinterpret_cast<short8v*>(&Als[r * 264 + (16 + g) * 8]) = val;
  }
  __syncthreads();

  const int lm = l & 15;
  const int lq = l >> 4;

  float4v acc[8];
  #pragma unroll
  for (int n = 0; n < 8; ++n) acc[n] = (float4v)0.f;

  const short8v* wp = reinterpret_cast<const short8v*>(wpack);
  #pragma unroll
  for (int ks = 0; ks < 8; ++ks) {
    short8v a = *reinterpret_cast<const short8v*>(
        &Als[(w * 16 + lm) * 264 + (ks * 4 + lq) * 8]);
    #pragma unroll
    for (int n = 0; n < 8; ++n) {
      short8v b = wp[(n * 8 + ks) * 64 + l];
      acc[n] = __builtin_amdgcn_mfma_f32_16x16x32_bf16(a, b, acc[n], 0, 0, 0);
    }
  }

  // Epilogue: + b_rel, store h (fp32), accumulate BN stats.
  #pragma unroll
  for (int n = 0; n < 8; ++n) {
    int col = n * 16 + lm;
    float bv = brel[col];
    float ps = 0.f, pq = 0.f;
    #pragma unroll
    for (int r = 0; r < 4; ++r) {
      int grow = row0 + w * 16 + lq * 4 + r;
      if (grow < NN) {
        float v = acc[n][r] + bv;
        h[(size_t)grow * DD + col] = v;
        ps += v; pq += v * v;
      }
    }
    atomicAdd(&s_sum[col], ps);
    atomicAdd(&s_sq[col], pq);
  }
  __syncthreads();
  if (t < DD) {
    atomicAdd(&gsum[t], s_sum[t]);
    atomicAdd(&gsq[t], s_sq[t]);
  }
}

// ---------------------------------------------------------------------------
// Phase 3: out = relu((h - mean) * rsqrt(var + eps) * gamma + beta) + x
// ---------------------------------------------------------------------------
__global__ __launch_bounds__(256) void bn_relu_res_kernel(
    const float* __restrict__ x, const float* __restrict__ gamma,
    const float* __restrict__ beta, const float* __restrict__ gsum,
    const float* __restrict__ gsq, float* __restrict__ out) {
  __shared__ float sc[DD];
  __shared__ float sh[DD];
  const int t = threadIdx.x;
  if (t < DD) {
    float mean = gsum[t] * (1.f / NN);
    float var = gsq[t] * (1.f / NN) - mean * mean;
    float rstd = rsqrtf(var + BN_EPS);
    float s = gamma[t] * rstd;
    sc[t] = s;
    sh[t] = beta[t] - mean * s;
  }
  __syncthreads();
  const int total4 = NN * DD / 4;
  for (int i = blockIdx.x * 256 + t; i < total4; i += gridDim.x * 256) {
    float4 h4 = reinterpret_cast<const float4*>(out)[i];
    float4 x4 = reinterpret_cast<const float4*>(x)[i];
    int c = (i & 31) << 2;
    float4 o;
    o.x = fmaxf(h4.x * sc[c + 0] + sh[c + 0], 0.f) + x4.x;
    o.y = fmaxf(h4.y * sc[c + 1] + sh[c + 1], 0.f) + x4.y;
    o.z = fmaxf(h4.z * sc[c + 2] + sh[c + 2], 0.f) + x4.z;
    o.w = fmaxf(h4.w * sc[c + 3] + sh[c + 3], 0.f) + x4.w;
    reinterpret_cast<float4*>(out)[i] = o;
  }
}

// ---------------------------------------------------------------------------
extern "C" void kernel_launch(void* const* d_in, const int* in_sizes, int n_in,
                              void* d_out, int out_size, void* d_ws, size_t ws_size,
                              hipStream_t stream) {
  const float* x     = (const float*)d_in[0];
  const int*   ei    = (const int*)d_in[1];
  const float* ew    = (const float*)d_in[2];
  const float* Wrel  = (const float*)d_in[3];
  const float* brel  = (const float*)d_in[4];
  const float* Wroot = (const float*)d_in[5];
  const float* gamma = (const float*)d_in[6];
  const float* beta  = (const float*)d_in[7];
  float* out = (float*)d_out;

  // ws layout (~33.4 MB): deg | gsum | gsq | offs | cursor | bsum | bofs |
  //                       sorted u32 | wpack bf16 | x16 bf16
  char* p = (char*)d_ws;
  int*   deg    = (int*)p;    p += (size_t)NN * 4;
  float* gsum   = (float*)p;  p += DD * 4;
  float* gsq    = (float*)p;  p += DD * 4;
  int*   offs   = (int*)p;    p += (size_t)NN * 4;
  int*   cursor = (int*)p;    p += (size_t)NN * 4;
  int*   bsum   = (int*)p;    p += NB * 4;
  int*   bofs   = (int*)p;    p += NB * 4;
  p = (char*)(((size_t)p + 15) & ~(size_t)15);
  unsigned* sorted = (unsigned*)p;             p += (size_t)NE * 4;
  unsigned short* wpack = (unsigned short*)p;  p += (size_t)8 * 8 * 64 * 8 * 2;
  p = (char*)(((size_t)p + 15) & ~(size_t)15);
  unsigned short* x16 = (unsigned short*)p;    p += (size_t)NN * DD * 2;

  // zero: deg + gsum + gsq (contiguous head of ws)
  hipMemsetAsync(d_ws, 0, (size_t)(NN + 2 * DD) * sizeof(int), stream);

  const int eblocks = (NE + 255) / 256;   // 6250
  x2bf_kernel<<<(NN * DD / 8 + 255) / 256, 256, 0, stream>>>(x, x16);
  hist_kernel<<<eblocks, 256, 0, stream>>>(ei, deg);
  scan_part_kernel<<<NB, 256, 0, stream>>>(deg, bsum);
  scan_block_kernel<<<1, 512, 0, stream>>>(bsum, bofs);
  scan_write_kernel<<<NB, 256, 0, stream>>>(deg, bofs, offs, cursor);
  bucket_kernel<<<2048, 256, 0, stream>>>(ei, ew, cursor, sorted);
  pack_w_kernel<<<8, 256, 0, stream>>>(Wrel, Wroot, wpack);
  fused_aggr_gemm_bn_kernel<<<MB, 256, 0, stream>>>(
      x16, sorted, offs, cursor, wpack, brel, out, gsum, gsq);
  bn_relu_res_kernel<<<2048, 256, 0, stream>>>(x, gamma, beta, gsum, gsq, out);
}

// Round 11
// 514.115 us; speedup vs baseline: 1.0140x; 1.0140x over previous
//
#include <hip/hip_runtime.h>

#define NN 100000
#define NE 1600000
#define DD 128
#define BN_EPS 1e-5f
#define NB 391       // scan blocks: 391*256 = 100096 >= NN
#define MB 1563      // gemm blocks: 1563*64 >= NN

typedef __attribute__((ext_vector_type(8))) short short8v;
typedef __attribute__((ext_vector_type(4))) float float4v;

__device__ inline unsigned short f2bf(float f) {
  unsigned u = __float_as_uint(f);
  return (unsigned short)((u + 0x7FFF + ((u >> 16) & 1)) >> 16);  // RNE
}
__device__ inline short8v pack8(float4 a, float4 b) {
  short8v o;
  o[0] = (short)f2bf(a.x); o[1] = (short)f2bf(a.y);
  o[2] = (short)f2bf(a.z); o[3] = (short)f2bf(a.w);
  o[4] = (short)f2bf(b.x); o[5] = (short)f2bf(b.y);
  o[6] = (short)f2bf(b.z); o[7] = (short)f2bf(b.w);
  return o;
}

// ---------------------------------------------------------------------------
// Phase 1a: histogram of dst degrees
// ---------------------------------------------------------------------------
__global__ __launch_bounds__(256) void hist_kernel(
    const int* __restrict__ ei, int* __restrict__ deg) {
  int e = blockIdx.x * 256 + threadIdx.x;
  if (e >= NE) return;
  atomicAdd(&deg[ei[NE + e]], 1);
}

// ---------------------------------------------------------------------------
// Phase 1b: device-wide exclusive scan of deg, 3 tiny kernels.
// ---------------------------------------------------------------------------
__global__ __launch_bounds__(256) void scan_part_kernel(
    const int* __restrict__ deg, int* __restrict__ bsum) {
  __shared__ int sc[256];
  int t = threadIdx.x;
  int i = blockIdx.x * 256 + t;
  int v = (i < NN) ? deg[i] : 0;
  sc[t] = v;
  __syncthreads();
  #pragma unroll
  for (int d = 1; d < 256; d <<= 1) {
    int u = (t >= d) ? sc[t - d] : 0;
    __syncthreads();
    sc[t] += u;
    __syncthreads();
  }
  if (t == 255) bsum[blockIdx.x] = sc[255];
}

__global__ __launch_bounds__(512) void scan_block_kernel(
    int* __restrict__ bsum, int* __restrict__ bofs) {
  __shared__ int sc[512];
  int t = threadIdx.x;
  int v = (t < NB) ? bsum[t] : 0;
  sc[t] = v;
  __syncthreads();
  #pragma unroll
  for (int d = 1; d < 512; d <<= 1) {
    int u = (t >= d) ? sc[t - d] : 0;
    __syncthreads();
    sc[t] += u;
    __syncthreads();
  }
  if (t < NB) bofs[t] = sc[t] - v;   // exclusive
}

__global__ __launch_bounds__(256) void scan_write_kernel(
    const int* __restrict__ deg, const int* __restrict__ bofs,
    int* __restrict__ offs, int* __restrict__ cursor) {
  __shared__ int sc[256];
  int t = threadIdx.x;
  int i = blockIdx.x * 256 + t;
  int v = (i < NN) ? deg[i] : 0;
  sc[t] = v;
  __syncthreads();
  #pragma unroll
  for (int d = 1; d < 256; d <<= 1) {
    int u = (t >= d) ? sc[t - d] : 0;
    __syncthreads();
    sc[t] += u;
    __syncthreads();
  }
  if (i < NN) {
    int excl = sc[t] - v + bofs[blockIdx.x];
    offs[i] = excl;
    cursor[i] = excl;
  }
}

// ---------------------------------------------------------------------------
// Phase 1c: bucket edges by dst (simple single pass; the XCD-partitioned
// variant from R9/R10 regressed — 8x edge rescan cost more than line-merge
// saved). Payload: (src:17b << 15) | bf16(w):15b (w >= 0, sign bit free).
// ---------------------------------------------------------------------------
__global__ __launch_bounds__(256) void bucket_kernel(
    const int* __restrict__ ei, const float* __restrict__ ew,
    int* __restrict__ cursor, unsigned* __restrict__ sorted) {
  int e = blockIdx.x * 256 + threadIdx.x;
  if (e >= NE) return;
  int src = ei[e];
  int dst = ei[NE + e];
  unsigned w15 = f2bf(ew[e]);              // sign bit is 0
  int pos = atomicAdd(&cursor[dst], 1);
  sorted[pos] = ((unsigned)src << 15) | w15;
}

// ---------------------------------------------------------------------------
// Phase 1d: gather-aggregate, fp32 x, one wave per node. Lanes 0-31 even
// edges / 32-63 odd edges, float4 (16 B) per lane. Manual 2-deep unroll:
// both sorted[] entries and both x rows issued before use -> halves the
// dependent-load chain depth (latency-bound phase). fp32 accumulate;
// halves combined via __shfl_xor; row written bf16 for the MFMA GEMM.
// ---------------------------------------------------------------------------
__global__ __launch_bounds__(256) void aggregate_kernel(
    const float* __restrict__ x, const unsigned* __restrict__ sorted,
    const int* __restrict__ offs, const int* __restrict__ cursor,
    unsigned short* __restrict__ aggr16) {
  int wid = (blockIdx.x * 256 + threadIdx.x) >> 6;   // wave id == node id
  int lane = threadIdx.x & 63;
  int half = lane >> 5;
  int l32 = lane & 31;
  if (wid >= NN) return;
  int s = offs[wid];
  int e = cursor[wid];
  const float4* xp = reinterpret_cast<const float4*>(x);
  float4 acc = make_float4(0.f, 0.f, 0.f, 0.f);
  int i = s + half;
  for (; i + 2 < e; i += 4) {        // process i and i+2 together
    unsigned p0 = sorted[i];
    unsigned p1 = sorted[i + 2];
    unsigned s0 = p0 >> 15;
    unsigned s1 = p1 >> 15;
    float4 v0 = xp[(size_t)s0 * 32 + l32];
    float4 v1 = xp[(size_t)s1 * 32 + l32];
    float w0 = __uint_as_float((p0 & 0x7FFFu) << 16);
    float w1 = __uint_as_float((p1 & 0x7FFFu) << 16);
    acc.x += w0 * v0.x + w1 * v1.x;
    acc.y += w0 * v0.y + w1 * v1.y;
    acc.z += w0 * v0.z + w1 * v1.z;
    acc.w += w0 * v0.w + w1 * v1.w;
  }
  if (i < e) {
    unsigned p0 = sorted[i];
    float w0 = __uint_as_float((p0 & 0x7FFFu) << 16);
    float4 v0 = xp[(size_t)(p0 >> 15) * 32 + l32];
    acc.x += w0 * v0.x; acc.y += w0 * v0.y;
    acc.z += w0 * v0.z; acc.w += w0 * v0.w;
  }
  acc.x += __shfl_xor(acc.x, 32, 64);
  acc.y += __shfl_xor(acc.y, 32, 64);
  acc.z += __shfl_xor(acc.z, 32, 64);
  acc.w += __shfl_xor(acc.w, 32, 64);
  if (half == 0) {
    ushort4 o;
    o.x = f2bf(acc.x); o.y = f2bf(acc.y);
    o.z = f2bf(acc.z); o.w = f2bf(acc.w);
    reinterpret_cast<ushort4*>(aggr16)[(size_t)wid * 32 + l32] = o;
  }
}

// ---------------------------------------------------------------------------
// Pack [Wrel; Wroot] (256x128 fp32) into MFMA-B fragment order, bf16.
// Frag (n, ks): lane l, j=0..7 -> B[ks*32 + (l>>4)*8 + j][n*16 + (l&15)].
// ---------------------------------------------------------------------------
__global__ __launch_bounds__(256) void pack_w_kernel(
    const float* __restrict__ Wrel, const float* __restrict__ Wroot,
    unsigned short* __restrict__ wpack) {
  int n = blockIdx.x;                 // 0..7
  for (int idx = threadIdx.x; idx < 8 * 64; idx += 256) {
    int ks = idx >> 6;
    int l = idx & 63;
    int srcN = n * 16 + (l & 15);
    short8v o;
    #pragma unroll
    for (int j = 0; j < 8; ++j) {
      int srcK = ks * 32 + ((l >> 4) << 3) + j;
      float v = (srcK < DD) ? Wrel[srcK * DD + srcN]
                            : Wroot[(srcK - DD) * DD + srcN];
      o[j] = (short)f2bf(v);
    }
    *reinterpret_cast<short8v*>(&wpack[(((size_t)(n * 8 + ks)) * 64 + l) * 8]) = o;
  }
}

// ---------------------------------------------------------------------------
// Phase 2: h = [aggr16 | bf16(x)] @ wpack + b_rel via MFMA 16x16x32 bf16.
// Block: 4 waves x 16 rows = 64 rows, N=128 full width, K=256 (8 k-steps).
// A staged in LDS, row stride 264 shorts (+8 pad). Fused BN statistics.
// ---------------------------------------------------------------------------
__global__ __launch_bounds__(256) void mfma_gemm_bn_stats_kernel(
    const unsigned short* __restrict__ aggr16, const float* __restrict__ x,
    const unsigned short* __restrict__ wpack, const float* __restrict__ brel,
    float* __restrict__ h, float* __restrict__ gsum, float* __restrict__ gsq) {
  __shared__ short Als[64 * 264];   // 33792 B
  __shared__ float s_sum[DD];
  __shared__ float s_sq[DD];

  const int t = threadIdx.x;
  const int row0 = blockIdx.x * 64;

  if (t < DD) { s_sum[t] = 0.f; s_sq[t] = 0.f; }

  for (int i = t; i < 64 * 32; i += 256) {
    int r = i >> 5;
    int g = i & 31;
    int grow = row0 + r;
    short8v val = (short8v)0;
    if (grow < NN) {
      if (g < 16) {
        val = *reinterpret_cast<const short8v*>(
            &aggr16[(size_t)grow * DD + g * 8]);
      } else {
        float4 f0 = reinterpret_cast<const float4*>(x)[(size_t)grow * 32 + (g - 16) * 2];
        float4 f1 = reinterpret_cast<const float4*>(x)[(size_t)grow * 32 + (g - 16) * 2 + 1];
        val = pack8(f0, f1);
      }
    }
    *reinterpret_cast<short8v*>(&Als[r * 264 + g * 8]) = val;
  }
  __syncthreads();

  const int w = t >> 6;      // wave 0..3 -> rows [w*16, w*16+16)
  const int l = t & 63;
  const int lm = l & 15;
  const int lq = l >> 4;

  float4v acc[8];
  #pragma unroll
  for (int n = 0; n < 8; ++n) acc[n] = (float4v)0.f;

  const short8v* wp = reinterpret_cast<const short8v*>(wpack);
  #pragma unroll
  for (int ks = 0; ks < 8; ++ks) {
    short8v a = *reinterpret_cast<const short8v*>(
        &Als[(w * 16 + lm) * 264 + (ks * 4 + lq) * 8]);
    #pragma unroll
    for (int n = 0; n < 8; ++n) {
      short8v b = wp[(n * 8 + ks) * 64 + l];
      acc[n] = __builtin_amdgcn_mfma_f32_16x16x32_bf16(a, b, acc[n], 0, 0, 0);
    }
  }

  #pragma unroll
  for (int n = 0; n < 8; ++n) {
    int col = n * 16 + lm;
    float bv = brel[col];
    float ps = 0.f, pq = 0.f;
    #pragma unroll
    for (int r = 0; r < 4; ++r) {
      int grow = row0 + w * 16 + lq * 4 + r;
      if (grow < NN) {
        float v = acc[n][r] + bv;
        h[(size_t)grow * DD + col] = v;
        ps += v; pq += v * v;
      }
    }
    atomicAdd(&s_sum[col], ps);
    atomicAdd(&s_sq[col], pq);
  }
  __syncthreads();
  if (t < DD) {
    atomicAdd(&gsum[t], s_sum[t]);
    atomicAdd(&gsq[t], s_sq[t]);
  }
}

// ---------------------------------------------------------------------------
// Phase 3: out = relu((h - mean) * rsqrt(var + eps) * gamma + beta) + x
// ---------------------------------------------------------------------------
__global__ __launch_bounds__(256) void bn_relu_res_kernel(
    const float* __restrict__ x, const float* __restrict__ gamma,
    const float* __restrict__ beta, const float* __restrict__ gsum,
    const float* __restrict__ gsq, float* __restrict__ out) {
  __shared__ float sc[DD];
  __shared__ float sh[DD];
  const int t = threadIdx.x;
  if (t < DD) {
    float mean = gsum[t] * (1.f / NN);
    float var = gsq[t] * (1.f / NN) - mean * mean;
    float rstd = rsqrtf(var + BN_EPS);
    float s = gamma[t] * rstd;
    sc[t] = s;
    sh[t] = beta[t] - mean * s;
  }
  __syncthreads();
  const int total4 = NN * DD / 4;
  for (int i = blockIdx.x * 256 + t; i < total4; i += gridDim.x * 256) {
    float4 h4 = reinterpret_cast<const float4*>(out)[i];
    float4 x4 = reinterpret_cast<const float4*>(x)[i];
    int c = (i & 31) << 2;
    float4 o;
    o.x = fmaxf(h4.x * sc[c + 0] + sh[c + 0], 0.f) + x4.x;
    o.y = fmaxf(h4.y * sc[c + 1] + sh[c + 1], 0.f) + x4.y;
    o.z = fmaxf(h4.z * sc[c + 2] + sh[c + 2], 0.f) + x4.z;
    o.w = fmaxf(h4.w * sc[c + 3] + sh[c + 3], 0.f) + x4.w;
    reinterpret_cast<float4*>(out)[i] = o;
  }
}

// ---------------------------------------------------------------------------
extern "C" void kernel_launch(void* const* d_in, const int* in_sizes, int n_in,
                              void* d_out, int out_size, void* d_ws, size_t ws_size,
                              hipStream_t stream) {
  const float* x     = (const float*)d_in[0];
  const int*   ei    = (const int*)d_in[1];
  const float* ew    = (const float*)d_in[2];
  const float* Wrel  = (const float*)d_in[3];
  const float* brel  = (const float*)d_in[4];
  const float* Wroot = (const float*)d_in[5];
  const float* gamma = (const float*)d_in[6];
  const float* beta  = (const float*)d_in[7];
  float* out = (float*)d_out;

  // ws layout (~33.3 MB): deg | gsum | gsq | offs | cursor | bsum | bofs |
  //                       sorted u32 | aggr16 bf16 | wpack bf16
  char* p = (char*)d_ws;
  int*   deg    = (int*)p;    p += (size_t)NN * 4;
  float* gsum   = (float*)p;  p += DD * 4;
  float* gsq    = (float*)p;  p += DD * 4;
  int*   offs   = (int*)p;    p += (size_t)NN * 4;
  int*   cursor = (int*)p;    p += (size_t)NN * 4;
  int*   bsum   = (int*)p;    p += NB * 4;
  int*   bofs   = (int*)p;    p += NB * 4;
  p = (char*)(((size_t)p + 15) & ~(size_t)15);
  unsigned* sorted = (unsigned*)p;             p += (size_t)NE * 4;
  unsigned short* aggr16 = (unsigned short*)p; p += (size_t)NN * DD * 2;
  unsigned short* wpack  = (unsigned short*)p; p += (size_t)8 * 8 * 64 * 8 * 2;

  // zero: deg + gsum + gsq (contiguous head of ws)
  hipMemsetAsync(d_ws, 0, (size_t)(NN + 2 * DD) * sizeof(int), stream);

  const int eblocks = (NE + 255) / 256;   // 6250
  hist_kernel<<<eblocks, 256, 0, stream>>>(ei, deg);
  scan_part_kernel<<<NB, 256, 0, stream>>>(deg, bsum);
  scan_block_kernel<<<1, 512, 0, stream>>>(bsum, bofs);
  scan_write_kernel<<<NB, 256, 0, stream>>>(deg, bofs, offs, cursor);
  bucket_kernel<<<eblocks, 256, 0, stream>>>(ei, ew, cursor, sorted);
  pack_w_kernel<<<8, 256, 0, stream>>>(Wrel, Wroot, wpack);
  {
    const int blocks = (NN * 64 + 255) / 256;  // 25000, one wave per node
    aggregate_kernel<<<blocks, 256, 0, stream>>>(x, sorted, offs, cursor, aggr16);
  }
  mfma_gemm_bn_stats_kernel<<<MB, 256, 0, stream>>>(
      aggr16, x, wpack, brel, out, gsum, gsq);
  bn_relu_res_kernel<<<2048, 256, 0, stream>>>(x, gamma, beta, gsum, gsq, out);
}

// Round 12
// 492.205 us; speedup vs baseline: 1.0592x; 1.0445x over previous
//
#include <hip/hip_runtime.h>

#define NN 100000
#define NE 1600000
#define DD 128
#define BN_EPS 1e-5f
#define NB 391       // scan blocks: 391*256 = 100096 >= NN
#define MB 1563      // gemm blocks: 1563*64 >= NN

typedef __attribute__((ext_vector_type(8))) short short8v;
typedef __attribute__((ext_vector_type(4))) float float4v;

__device__ inline unsigned short f2bf(float f) {
  unsigned u = __float_as_uint(f);
  return (unsigned short)((u + 0x7FFF + ((u >> 16) & 1)) >> 16);  // RNE
}
__device__ inline short8v pack8(float4 a, float4 b) {
  short8v o;
  o[0] = (short)f2bf(a.x); o[1] = (short)f2bf(a.y);
  o[2] = (short)f2bf(a.z); o[3] = (short)f2bf(a.w);
  o[4] = (short)f2bf(b.x); o[5] = (short)f2bf(b.y);
  o[6] = (short)f2bf(b.z); o[7] = (short)f2bf(b.w);
  return o;
}

// ---------------------------------------------------------------------------
// Phase 0: x (fp32) -> x16 (bf16). x16 lives in d_out, which is dead until
// the GEMM writes h (aggregate completes first on the same stream -> no race).
// ---------------------------------------------------------------------------
__global__ __launch_bounds__(256) void x2bf_kernel(
    const float* __restrict__ x, unsigned short* __restrict__ x16) {
  int i = blockIdx.x * 256 + threadIdx.x;       // one short8 per thread
  if (i >= NN * DD / 8) return;
  float4 f0 = reinterpret_cast<const float4*>(x)[(size_t)i * 2];
  float4 f1 = reinterpret_cast<const float4*>(x)[(size_t)i * 2 + 1];
  reinterpret_cast<short8v*>(x16)[i] = pack8(f0, f1);
}

// ---------------------------------------------------------------------------
// Phase 1a: histogram of dst degrees
// ---------------------------------------------------------------------------
__global__ __launch_bounds__(256) void hist_kernel(
    const int* __restrict__ ei, int* __restrict__ deg) {
  int e = blockIdx.x * 256 + threadIdx.x;
  if (e >= NE) return;
  atomicAdd(&deg[ei[NE + e]], 1);
}

// ---------------------------------------------------------------------------
// Phase 1b: device-wide exclusive scan of deg, 3 tiny kernels.
// ---------------------------------------------------------------------------
__global__ __launch_bounds__(256) void scan_part_kernel(
    const int* __restrict__ deg, int* __restrict__ bsum) {
  __shared__ int sc[256];
  int t = threadIdx.x;
  int i = blockIdx.x * 256 + t;
  int v = (i < NN) ? deg[i] : 0;
  sc[t] = v;
  __syncthreads();
  #pragma unroll
  for (int d = 1; d < 256; d <<= 1) {
    int u = (t >= d) ? sc[t - d] : 0;
    __syncthreads();
    sc[t] += u;
    __syncthreads();
  }
  if (t == 255) bsum[blockIdx.x] = sc[255];
}

__global__ __launch_bounds__(512) void scan_block_kernel(
    int* __restrict__ bsum, int* __restrict__ bofs) {
  __shared__ int sc[512];
  int t = threadIdx.x;
  int v = (t < NB) ? bsum[t] : 0;
  sc[t] = v;
  __syncthreads();
  #pragma unroll
  for (int d = 1; d < 512; d <<= 1) {
    int u = (t >= d) ? sc[t - d] : 0;
    __syncthreads();
    sc[t] += u;
    __syncthreads();
  }
  if (t < NB) bofs[t] = sc[t] - v;   // exclusive
}

__global__ __launch_bounds__(256) void scan_write_kernel(
    const int* __restrict__ deg, const int* __restrict__ bofs,
    int* __restrict__ offs, int* __restrict__ cursor) {
  __shared__ int sc[256];
  int t = threadIdx.x;
  int i = blockIdx.x * 256 + t;
  int v = (i < NN) ? deg[i] : 0;
  sc[t] = v;
  __syncthreads();
  #pragma unroll
  for (int d = 1; d < 256; d <<= 1) {
    int u = (t >= d) ? sc[t - d] : 0;
    __syncthreads();
    sc[t] += u;
    __syncthreads();
  }
  if (i < NN) {
    int excl = sc[t] - v + bofs[blockIdx.x];
    offs[i] = excl;
    cursor[i] = excl;
  }
}

// ---------------------------------------------------------------------------
// Phase 1c: bucket edges by dst (simple single pass).
// Payload: (src:17b << 15) | bf16(w):15b (w >= 0, sign bit free).
// ---------------------------------------------------------------------------
__global__ __launch_bounds__(256) void bucket_kernel(
    const int* __restrict__ ei, const float* __restrict__ ew,
    int* __restrict__ cursor, unsigned* __restrict__ sorted) {
  int e = blockIdx.x * 256 + threadIdx.x;
  if (e >= NE) return;
  int src = ei[e];
  int dst = ei[NE + e];
  unsigned w15 = f2bf(ew[e]);              // sign bit is 0
  int pos = atomicAdd(&cursor[dst], 1);
  sorted[pos] = ((unsigned)src << 15) | w15;
}

// ---------------------------------------------------------------------------
// Phase 1d: gather-aggregate from bf16 x16 (256 B/row instead of 512).
// One wave per node; lanes 0-31 even edges / 32-63 odd edges; uint2 (8 B,
// 4 bf16 cols) per lane; manual 2-deep unroll halves the dependent-load
// chain; fp32 accumulate; halves combined via __shfl_xor; row written bf16.
// ---------------------------------------------------------------------------
__global__ __launch_bounds__(256) void aggregate16_kernel(
    const unsigned short* __restrict__ x16, const unsigned* __restrict__ sorted,
    const int* __restrict__ offs, const int* __restrict__ cursor,
    unsigned short* __restrict__ aggr16) {
  int wid = (blockIdx.x * 256 + threadIdx.x) >> 6;   // wave id == node id
  int lane = threadIdx.x & 63;
  int half = lane >> 5;
  int l32 = lane & 31;         // cols l32*4 .. l32*4+3
  if (wid >= NN) return;
  int s = offs[wid];
  int e = cursor[wid];
  const uint2* xp = reinterpret_cast<const uint2*>(x16);
  float a0 = 0.f, a1 = 0.f, a2 = 0.f, a3 = 0.f;
  int i = s + half;
  for (; i + 2 < e; i += 4) {        // process i and i+2 together
    unsigned p0 = sorted[i];
    unsigned p1 = sorted[i + 2];
    uint2 v0 = xp[(size_t)(p0 >> 15) * 32 + l32];
    uint2 v1 = xp[(size_t)(p1 >> 15) * 32 + l32];
    float w0 = __uint_as_float((p0 & 0x7FFFu) << 16);
    float w1 = __uint_as_float((p1 & 0x7FFFu) << 16);
    a0 += w0 * __uint_as_float(v0.x << 16) + w1 * __uint_as_float(v1.x << 16);
    a1 += w0 * __uint_as_float(v0.x & 0xFFFF0000u)
        + w1 * __uint_as_float(v1.x & 0xFFFF0000u);
    a2 += w0 * __uint_as_float(v0.y << 16) + w1 * __uint_as_float(v1.y << 16);
    a3 += w0 * __uint_as_float(v0.y & 0xFFFF0000u)
        + w1 * __uint_as_float(v1.y & 0xFFFF0000u);
  }
  if (i < e) {
    unsigned p0 = sorted[i];
    float w0 = __uint_as_float((p0 & 0x7FFFu) << 16);
    uint2 v0 = xp[(size_t)(p0 >> 15) * 32 + l32];
    a0 += w0 * __uint_as_float(v0.x << 16);
    a1 += w0 * __uint_as_float(v0.x & 0xFFFF0000u);
    a2 += w0 * __uint_as_float(v0.y << 16);
    a3 += w0 * __uint_as_float(v0.y & 0xFFFF0000u);
  }
  a0 += __shfl_xor(a0, 32, 64);
  a1 += __shfl_xor(a1, 32, 64);
  a2 += __shfl_xor(a2, 32, 64);
  a3 += __shfl_xor(a3, 32, 64);
  if (half == 0) {
    ushort4 o;
    o.x = f2bf(a0); o.y = f2bf(a1); o.z = f2bf(a2); o.w = f2bf(a3);
    reinterpret_cast<ushort4*>(aggr16)[(size_t)wid * 32 + l32] = o;
  }
}

// ---------------------------------------------------------------------------
// Pack [Wrel; Wroot] (256x128 fp32) into MFMA-B fragment order, bf16.
// Frag (n, ks): lane l, j=0..7 -> B[ks*32 + (l>>4)*8 + j][n*16 + (l&15)].
// ---------------------------------------------------------------------------
__global__ __launch_bounds__(256) void pack_w_kernel(
    const float* __restrict__ Wrel, const float* __restrict__ Wroot,
    unsigned short* __restrict__ wpack) {
  int n = blockIdx.x;                 // 0..7
  for (int idx = threadIdx.x; idx < 8 * 64; idx += 256) {
    int ks = idx >> 6;
    int l = idx & 63;
    int srcN = n * 16 + (l & 15);
    short8v o;
    #pragma unroll
    for (int j = 0; j < 8; ++j) {
      int srcK = ks * 32 + ((l >> 4) << 3) + j;
      float v = (srcK < DD) ? Wrel[srcK * DD + srcN]
                            : Wroot[(srcK - DD) * DD + srcN];
      o[j] = (short)f2bf(v);
    }
    *reinterpret_cast<short8v*>(&wpack[(((size_t)(n * 8 + ks)) * 64 + l) * 8]) = o;
  }
}

// ---------------------------------------------------------------------------
// Phase 2: h = [aggr16 | bf16(x)] @ wpack + b_rel via MFMA 16x16x32 bf16.
// Block: 4 waves x 16 rows = 64 rows, N=128 full width, K=256 (8 k-steps).
// A staged in LDS, row stride 264 shorts (+8 pad). Fused BN statistics.
// h overwrites d_out (x16 region) — safe, aggregate has already consumed it.
// ---------------------------------------------------------------------------
__global__ __launch_bounds__(256) void mfma_gemm_bn_stats_kernel(
    const unsigned short* __restrict__ aggr16, const float* __restrict__ x,
    const unsigned short* __restrict__ wpack, const float* __restrict__ brel,
    float* __restrict__ h, float* __restrict__ gsum, float* __restrict__ gsq) {
  __shared__ short Als[64 * 264];   // 33792 B
  __shared__ float s_sum[DD];
  __shared__ float s_sq[DD];

  const int t = threadIdx.x;
  const int row0 = blockIdx.x * 64;

  if (t < DD) { s_sum[t] = 0.f; s_sq[t] = 0.f; }

  for (int i = t; i < 64 * 32; i += 256) {
    int r = i >> 5;
    int g = i & 31;
    int grow = row0 + r;
    short8v val = (short8v)0;
    if (grow < NN) {
      if (g < 16) {
        val = *reinterpret_cast<const short8v*>(
            &aggr16[(size_t)grow * DD + g * 8]);
      } else {
        float4 f0 = reinterpret_cast<const float4*>(x)[(size_t)grow * 32 + (g - 16) * 2];
        float4 f1 = reinterpret_cast<const float4*>(x)[(size_t)grow * 32 + (g - 16) * 2 + 1];
        val = pack8(f0, f1);
      }
    }
    *reinterpret_cast<short8v*>(&Als[r * 264 + g * 8]) = val;
  }
  __syncthreads();

  const int w = t >> 6;      // wave 0..3 -> rows [w*16, w*16+16)
  const int l = t & 63;
  const int lm = l & 15;
  const int lq = l >> 4;

  float4v acc[8];
  #pragma unroll
  for (int n = 0; n < 8; ++n) acc[n] = (float4v)0.f;

  const short8v* wp = reinterpret_cast<const short8v*>(wpack);
  #pragma unroll
  for (int ks = 0; ks < 8; ++ks) {
    short8v a = *reinterpret_cast<const short8v*>(
        &Als[(w * 16 + lm) * 264 + (ks * 4 + lq) * 8]);
    #pragma unroll
    for (int n = 0; n < 8; ++n) {
      short8v b = wp[(n * 8 + ks) * 64 + l];
      acc[n] = __builtin_amdgcn_mfma_f32_16x16x32_bf16(a, b, acc[n], 0, 0, 0);
    }
  }

  #pragma unroll
  for (int n = 0; n < 8; ++n) {
    int col = n * 16 + lm;
    float bv = brel[col];
    float ps = 0.f, pq = 0.f;
    #pragma unroll
    for (int r = 0; r < 4; ++r) {
      int grow = row0 + w * 16 + lq * 4 + r;
      if (grow < NN) {
        float v = acc[n][r] + bv;
        h[(size_t)grow * DD + col] = v;
        ps += v; pq += v * v;
      }
    }
    atomicAdd(&s_sum[col], ps);
    atomicAdd(&s_sq[col], pq);
  }
  __syncthreads();
  if (t < DD) {
    atomicAdd(&gsum[t], s_sum[t]);
    atomicAdd(&gsq[t], s_sq[t]);
  }
}

// ---------------------------------------------------------------------------
// Phase 3: out = relu((h - mean) * rsqrt(var + eps) * gamma + beta) + x
// ---------------------------------------------------------------------------
__global__ __launch_bounds__(256) void bn_relu_res_kernel(
    const float* __restrict__ x, const float* __restrict__ gamma,
    const float* __restrict__ beta, const float* __restrict__ gsum,
    const float* __restrict__ gsq, float* __restrict__ out) {
  __shared__ float sc[DD];
  __shared__ float sh[DD];
  const int t = threadIdx.x;
  if (t < DD) {
    float mean = gsum[t] * (1.f / NN);
    float var = gsq[t] * (1.f / NN) - mean * mean;
    float rstd = rsqrtf(var + BN_EPS);
    float s = gamma[t] * rstd;
    sc[t] = s;
    sh[t] = beta[t] - mean * s;
  }
  __syncthreads();
  const int total4 = NN * DD / 4;
  for (int i = blockIdx.x * 256 + t; i < total4; i += gridDim.x * 256) {
    float4 h4 = reinterpret_cast<const float4*>(out)[i];
    float4 x4 = reinterpret_cast<const float4*>(x)[i];
    int c = (i & 31) << 2;
    float4 o;
    o.x = fmaxf(h4.x * sc[c + 0] + sh[c + 0], 0.f) + x4.x;
    o.y = fmaxf(h4.y * sc[c + 1] + sh[c + 1], 0.f) + x4.y;
    o.z = fmaxf(h4.z * sc[c + 2] + sh[c + 2], 0.f) + x4.z;
    o.w = fmaxf(h4.w * sc[c + 3] + sh[c + 3], 0.f) + x4.w;
    reinterpret_cast<float4*>(out)[i] = o;
  }
}

// ---------------------------------------------------------------------------
extern "C" void kernel_launch(void* const* d_in, const int* in_sizes, int n_in,
                              void* d_out, int out_size, void* d_ws, size_t ws_size,
                              hipStream_t stream) {
  const float* x     = (const float*)d_in[0];
  const int*   ei    = (const int*)d_in[1];
  const float* ew    = (const float*)d_in[2];
  const float* Wrel  = (const float*)d_in[3];
  const float* brel  = (const float*)d_in[4];
  const float* Wroot = (const float*)d_in[5];
  const float* gamma = (const float*)d_in[6];
  const float* beta  = (const float*)d_in[7];
  float* out = (float*)d_out;

  // ws layout (~33.3 MB): deg | gsum | gsq | offs | cursor | bsum | bofs |
  //                       sorted u32 | aggr16 bf16 | wpack bf16
  char* p = (char*)d_ws;
  int*   deg    = (int*)p;    p += (size_t)NN * 4;
  float* gsum   = (float*)p;  p += DD * 4;
  float* gsq    = (float*)p;  p += DD * 4;
  int*   offs   = (int*)p;    p += (size_t)NN * 4;
  int*   cursor = (int*)p;    p += (size_t)NN * 4;
  int*   bsum   = (int*)p;    p += NB * 4;
  int*   bofs   = (int*)p;    p += NB * 4;
  p = (char*)(((size_t)p + 15) & ~(size_t)15);
  unsigned* sorted = (unsigned*)p;             p += (size_t)NE * 4;
  unsigned short* aggr16 = (unsigned short*)p; p += (size_t)NN * DD * 2;
  unsigned short* wpack  = (unsigned short*)p; p += (size_t)8 * 8 * 64 * 8 * 2;

  // x16 parks in d_out (dead until the GEMM writes h).
  unsigned short* x16 = (unsigned short*)d_out;

  // zero: deg + gsum + gsq (contiguous head of ws)
  hipMemsetAsync(d_ws, 0, (size_t)(NN + 2 * DD) * sizeof(int), stream);

  const int eblocks = (NE + 255) / 256;   // 6250
  x2bf_kernel<<<(NN * DD / 8 + 255) / 256, 256, 0, stream>>>(x, x16);
  hist_kernel<<<eblocks, 256, 0, stream>>>(ei, deg);
  scan_part_kernel<<<NB, 256, 0, stream>>>(deg, bsum);
  scan_block_kernel<<<1, 512, 0, stream>>>(bsum, bofs);
  scan_write_kernel<<<NB, 256, 0, stream>>>(deg, bofs, offs, cursor);
  bucket_kernel<<<eblocks, 256, 0, stream>>>(ei, ew, cursor, sorted);
  pack_w_kernel<<<8, 256, 0, stream>>>(Wrel, Wroot, wpack);
  {
    const int blocks = (NN * 64 + 255) / 256;  // 25000, one wave per node
    aggregate16_kernel<<<blocks, 256, 0, stream>>>(x16, sorted, offs, cursor,
                                                   aggr16);
  }
  mfma_gemm_bn_stats_kernel<<<MB, 256, 0, stream>>>(
      aggr16, x, wpack, brel, out, gsum, gsq);
  bn_relu_res_kernel<<<2048, 256, 0, stream>>>(x, gamma, beta, gsum, gsq, out);
}